// Round 1
// baseline (42.770 us; speedup 1.0000x reference)
//
#include <hip/hip_runtime.h>

#define NUM_IDS 64
#define NB 65           // bins 0..64 (0 = background)
#define HIST_BINS (NB * NB)

// Kernel 1: joint histogram C[p][t] over all pixels.
__global__ __launch_bounds__(256) void isl_hist_kernel(
    const int* __restrict__ pred, const int* __restrict__ tru,
    int* __restrict__ ghist, int n4) {
    __shared__ int lhist[HIST_BINS];
    for (int i = threadIdx.x; i < HIST_BINS; i += blockDim.x) lhist[i] = 0;
    __syncthreads();

    const int4* __restrict__ p4 = (const int4*)pred;
    const int4* __restrict__ t4 = (const int4*)tru;
    int idx = blockIdx.x * blockDim.x + threadIdx.x;
    int stride = gridDim.x * blockDim.x;
    for (int i = idx; i < n4; i += stride) {
        int4 p = p4[i];
        int4 t = t4[i];
        atomicAdd(&lhist[p.x * NB + t.x], 1);
        atomicAdd(&lhist[p.y * NB + t.y], 1);
        atomicAdd(&lhist[p.z * NB + t.z], 1);
        atomicAdd(&lhist[p.w * NB + t.w], 1);
    }
    __syncthreads();

    for (int i = threadIdx.x; i < HIST_BINS; i += blockDim.x) {
        int v = lhist[i];
        if (v) atomicAdd(&ghist[i], v);
    }
}

// Kernel 2: areas, IoU matrix, row/col maxes, final loss (single block).
__global__ __launch_bounds__(256) void isl_reduce_kernel(
    const int* __restrict__ ghist, float* __restrict__ out) {
    __shared__ int C[HIST_BINS];
    __shared__ float ap[NUM_IDS], at[NUM_IDS];
    __shared__ float rowmax[NUM_IDS], colmax[NUM_IDS];

    for (int i = threadIdx.x; i < HIST_BINS; i += blockDim.x) C[i] = ghist[i];
    __syncthreads();

    int t = threadIdx.x;
    if (t < NUM_IDS) {
        int s = 0;
        for (int j = 0; j < NB; ++j) s += C[(t + 1) * NB + j];
        ap[t] = (float)s;
        int s2 = 0;
        for (int i = 0; i < NB; ++i) s2 += C[i * NB + (t + 1)];
        at[t] = (float)s2;
    }
    __syncthreads();

    if (t < NUM_IDS) {
        float a = ap[t];
        float m = 0.f;
        for (int j = 0; j < NUM_IDS; ++j) {
            float inter = (float)C[(t + 1) * NB + (j + 1)];
            float uni = a + at[j] - inter;
            float iou = (uni > 0.f) ? inter / uni : 0.f;
            m = fmaxf(m, iou);
        }
        rowmax[t] = m;

        float b = at[t];
        float m2 = 0.f;
        for (int i = 0; i < NUM_IDS; ++i) {
            float inter = (float)C[(i + 1) * NB + (t + 1)];
            float uni = ap[i] + b - inter;
            float iou = (uni > 0.f) ? inter / uni : 0.f;
            m2 = fmaxf(m2, iou);
        }
        colmax[t] = m2;
    }
    __syncthreads();

    if (t == 0) {
        float loss = 0.f, cnt = 0.f;
        for (int i = 0; i < NUM_IDS; ++i) {
            if (ap[i] > 0.f) { loss += 1.f - rowmax[i]; cnt += 1.f; }
            if (at[i] > 0.f) { loss += 1.f - colmax[i]; cnt += 1.f; }
        }
        out[0] = (cnt > 0.f) ? loss / cnt : 0.f;
    }
}

extern "C" void kernel_launch(void* const* d_in, const int* in_sizes, int n_in,
                              void* d_out, int out_size, void* d_ws, size_t ws_size,
                              hipStream_t stream) {
    const int* pred = (const int*)d_in[0];
    const int* tru  = (const int*)d_in[1];
    float* out = (float*)d_out;
    int n = in_sizes[0];            // 1024*1024, divisible by 4
    int* ghist = (int*)d_ws;        // 4225 ints

    hipMemsetAsync(ghist, 0, HIST_BINS * sizeof(int), stream);
    isl_hist_kernel<<<128, 256, 0, stream>>>(pred, tru, ghist, n >> 2);
    isl_reduce_kernel<<<1, 256, 0, stream>>>(ghist, out);
}

// Round 2
// 38.420 us; speedup vs baseline: 1.1132x; 1.1132x over previous
//
#include <hip/hip_runtime.h>

#define NUM_IDS 64
#define NB 65              // bins 0..64 (0 = background)
#define HIST_BINS (NB * NB)   // 4225
#define PADBINS 4228          // padded to multiple of 4 for int4
#define GROUPS (PADBINS / 4)  // 1057
#define HB 32                 // histogram blocks
#define HT 512                // histogram threads/block

// Kernel 1: per-block joint histogram C[p][t], written to private slice of ws.
__global__ __launch_bounds__(HT) void isl_hist_kernel(
    const int* __restrict__ pred, const int* __restrict__ tru,
    int* __restrict__ part, int n4) {
    __shared__ int lh[PADBINS];
    for (int i = threadIdx.x; i < PADBINS; i += HT) lh[i] = 0;
    __syncthreads();

    const int4* __restrict__ p4 = (const int4*)pred;
    const int4* __restrict__ t4 = (const int4*)tru;
    int idx = blockIdx.x * HT + threadIdx.x;
    const int stride = HB * HT;
    int nfull = n4 / stride;
    int i = idx;
#pragma unroll 4
    for (int k = 0; k < nfull; ++k, i += stride) {
        int4 p = p4[i];
        int4 t = t4[i];
        atomicAdd(&lh[p.x * NB + t.x], 1);
        atomicAdd(&lh[p.y * NB + t.y], 1);
        atomicAdd(&lh[p.z * NB + t.z], 1);
        atomicAdd(&lh[p.w * NB + t.w], 1);
    }
    if (i < n4) {  // tail (absent for 1024x1024 but keep general)
        int4 p = p4[i];
        int4 t = t4[i];
        atomicAdd(&lh[p.x * NB + t.x], 1);
        atomicAdd(&lh[p.y * NB + t.y], 1);
        atomicAdd(&lh[p.z * NB + t.z], 1);
        atomicAdd(&lh[p.w * NB + t.w], 1);
    }
    __syncthreads();

    int base = blockIdx.x * PADBINS;
    for (int j = threadIdx.x; j < PADBINS; j += HT) part[base + j] = lh[j];
}

// Kernel 2: sum partials -> C, then areas, IoU maxes, final loss (one block).
__global__ __launch_bounds__(1024) void isl_reduce_kernel(
    const int* __restrict__ part, float* __restrict__ out) {
    __shared__ alignas(16) int C[PADBINS];
    __shared__ float ap[NUM_IDS], at[NUM_IDS];
    __shared__ float rowmax[NUM_IDS], colmax[NUM_IDS];

    int t = threadIdx.x;
    for (int g = t; g < GROUPS; g += 1024) {
        int4 s = make_int4(0, 0, 0, 0);
#pragma unroll 8
        for (int b = 0; b < HB; ++b) {
            const int4 v = *(const int4*)(part + b * PADBINS + (g << 2));
            s.x += v.x; s.y += v.y; s.z += v.z; s.w += v.w;
        }
        *(int4*)(&C[g << 2]) = s;
    }
    __syncthreads();

    if (t < NUM_IDS) {
        int s = 0;
        for (int j = 0; j < NB; ++j) s += C[(t + 1) * NB + j];
        ap[t] = (float)s;
        int s2 = 0;
        for (int i = 0; i < NB; ++i) s2 += C[i * NB + (t + 1)];
        at[t] = (float)s2;
    }
    __syncthreads();

    if (t < NUM_IDS) {
        float a = ap[t];
        float m = 0.f;
        for (int j = 0; j < NUM_IDS; ++j) {
            float inter = (float)C[(t + 1) * NB + (j + 1)];
            float uni = a + at[j] - inter;
            float iou = (uni > 0.f) ? inter / uni : 0.f;
            m = fmaxf(m, iou);
        }
        rowmax[t] = m;

        float b = at[t];
        float m2 = 0.f;
        for (int i = 0; i < NUM_IDS; ++i) {
            float inter = (float)C[(i + 1) * NB + (t + 1)];
            float uni = ap[i] + b - inter;
            float iou = (uni > 0.f) ? inter / uni : 0.f;
            m2 = fmaxf(m2, iou);
        }
        colmax[t] = m2;
    }
    __syncthreads();

    if (t == 0) {
        float loss = 0.f, cnt = 0.f;
        for (int i = 0; i < NUM_IDS; ++i) {
            if (ap[i] > 0.f) { loss += 1.f - rowmax[i]; cnt += 1.f; }
            if (at[i] > 0.f) { loss += 1.f - colmax[i]; cnt += 1.f; }
        }
        out[0] = (cnt > 0.f) ? loss / cnt : 0.f;
    }
}

extern "C" void kernel_launch(void* const* d_in, const int* in_sizes, int n_in,
                              void* d_out, int out_size, void* d_ws, size_t ws_size,
                              hipStream_t stream) {
    const int* pred = (const int*)d_in[0];
    const int* tru  = (const int*)d_in[1];
    float* out = (float*)d_out;
    int n = in_sizes[0];            // 1024*1024
    int* part = (int*)d_ws;         // HB * PADBINS ints = 541 KB

    isl_hist_kernel<<<HB, HT, 0, stream>>>(pred, tru, part, n >> 2);
    isl_reduce_kernel<<<1, 1024, 0, stream>>>(part, out);
}